// Round 11
// baseline (42.567 us; speedup 1.0000x reference)
//
#include <hip/hip_runtime.h>
#include <hip/hip_bf16.h>

// Problem constants (B=4, T=4096, C=2048, E=64)
#define N_TOK   16384
#define C_DIM   2048
#define E_DIM   64
#define P_OFF   (N_TOK * E_DIM)        // 1048576 — end of probs section
#define FB_OFF  P_OFF                  // fallback_count scalar
#define LG_OFF  (P_OFF + 1)            // logits section
#define AM_OFF  (2 * P_OFF + 1)        // activation_mask section

#define BPK_BYTES  262144              // 256 KB prepacked B
#define PART_BYTES ((size_t)8 * N_TOK * E_DIM * 2)   // 16.8 MB bf16 partials (split-K-8)

typedef __attribute__((ext_vector_type(8))) short bf16x8;  // 8 bf16 in 4 VGPRs
typedef __attribute__((ext_vector_type(4))) float f32x4;

static __device__ __forceinline__ unsigned short f2bf_rtn(float f) {
    unsigned u = __float_as_uint(f);
    unsigned r = u + 0x7FFFu + ((u >> 16) & 1u);   // round-to-nearest-even
    return (unsigned short)(r >> 16);
}
static __device__ __forceinline__ float bf2f(unsigned short h) {
    return __uint_as_float(((unsigned)h) << 16);
}
static __device__ __forceinline__ unsigned short f2bf_hw(float f) {
    __hip_bfloat16 h = __float2bfloat16(f);   // HW cvt; pairs fuse to v_cvt_pk_bf16_f32
    return *reinterpret_cast<unsigned short*>(&h);
}

// ---------------------------------------------------------------------------
// Kernel 1: prepack sim_matrix [2048,64] f32 -> bf16 (RTN) MFMA fragments.
// kk-step it (32 k): layout [it(64)][nb(4)][lane(64)][i(8)] shorts (256 KB).
// Content: lane l, elem i -> sim[it*32 + (l>>4)*8 + i][nb*16 + (l&15)]
// Also zero-initializes the fallback counter in d_out.
// ---------------------------------------------------------------------------
__global__ void gating_prepack(const float* __restrict__ sim,
                               unsigned short* __restrict__ Bpk,
                               float* __restrict__ out) {
    int tid = blockIdx.x * 256 + threadIdx.x;
    if (tid == 0) out[FB_OFF] = 0.0f;
    if (tid >= C_DIM * E_DIM) return;
    int k = tid >> 6;
    int e = tid & 63;
    float v = sim[tid];                       // sim[k*64 + e]
    int it = k >> 5;                          // kk-step 0..63
    int gr = (k >> 3) & 3;
    int i  = k & 7;
    int lane = gr * 16 + (e & 15);
    int nb   = e >> 4;
    Bpk[it * 2048 + nb * 512 + lane * 8 + i] = f2bf_rtn(v);
}

// ---------------------------------------------------------------------------
// Kernel 2 (R11): split-K-8 GEMM with A via global_load_lds (unsinkable DMA)
// and B fully LDS-resident (vmcnt-free in the loop).
//
// Why: R3-R10 were schedule-invariant because (1) register-destined loads get
// sunk to first use by hipcc (R3: VGPR=44 vs 64-reg ring in source) and
// (2) A and B shared the in-order vmcnt FIFO, so any B-wait drained younger
// A loads. Here: B is staged once (32 KB eighth) -> lgkmcnt only; A-DMAs are
// the SOLE vmcnt stream with counted s_waitcnt vmcnt(4/2/0), tri-buffered
// (2-step genuine prefetch distance, ~unsinkable by construction).
//
// Grid 1024 x 512 thr (8 waves). bid: kq=bid&7 (K-eighth), tg=bid>>3
// (128-token group). Wave w: tokens tg*128+w*16 .. +15, 8 kk-steps.
// LDS: 32 KB B + 8 waves x 3 bufs x 2 KB A = 80 KB -> 2 blocks/CU.
//
// A staging layout (per wave, per kk-step buf = 2 KB, 16 rows x 128 B):
//   LDS byte (r, o) holds x[token r][colbyte o ^ ((r&3)<<5)]  (src-side swz)
//   DMA instr j (j=0,1), lane l: dest = j*1024 + l*16 (linear, lane x 16B);
//     r = j*8 + (l>>3), o = (l&7)*16 -> src offset = o ^ ((r&3)<<5).
//   Frag read (g=l>>4, e0=l&15): row e0, cols g*8..+7 ->
//     byte = e0*128 + ((g*32) ^ ((e0&3)<<5))  [2x b128; ~4-way conflict, 1.6x]
// Writes bf16 partials: part[kq][t][e0(16)][nb(4)] (ushort4 per lane).
// ---------------------------------------------------------------------------
__global__ __launch_bounds__(512, 4)
void gating_gemm8(const float* __restrict__ x,
                  const unsigned short* __restrict__ Bpk,
                  unsigned short* __restrict__ part) {
    __shared__ __align__(16) unsigned short BldsU[16384];  // 32 KB: B eighth
    __shared__ __align__(16) char Alds[49152];             // 48 KB: A tri-buf x 8 waves

    const int tid = threadIdx.x;
    const int kq  = blockIdx.x & 7;
    const int tg  = blockIdx.x >> 3;
    const int l   = tid & 63;
    const int w   = tid >> 6;
    const int g   = l >> 4;
    const int e0  = l & 15;
    const int trow0 = tg * 128 + w * 16;

    // ---- stage B eighth: 4 DMAs (512 thr x 16 B = 8 KB each), linear ----
    const unsigned short* bq = Bpk + kq * 16384;
#pragma unroll
    for (int j = 0; j < 4; ++j) {
        __builtin_amdgcn_global_load_lds(
            (const __attribute__((address_space(1))) unsigned int*)(bq + j * 4096 + tid * 8),
            (__attribute__((address_space(3))) unsigned int*)(&BldsU[j * 4096 + tid * 8]),
            16, 0, 0);
    }

    // ---- A DMA addressing (per-lane, src-side swizzle) ----
    const int rsub = l >> 3;                      // row sub-index 0..7
    const int soff = ((((l & 7) * 16) ^ ((rsub & 3) << 5)) >> 2);  // f32 units
    const float* xbase = x + (size_t)trow0 * C_DIM + kq * 256;
    const float* src0 = xbase + (size_t)(0 + rsub) * C_DIM + soff;     // instr j=0: rows 0..7
    const float* src1 = xbase + (size_t)(8 + rsub) * C_DIM + soff;     // instr j=1: rows 8..15
    char* Aw = Alds + w * 6144;                   // this wave's 3 bufs
    const int dst_lane = l * 16;

    auto issueA = [&](int i) {                    // kk-step i -> buf i%3
        char* d = Aw + (i % 3) * 2048;
        __builtin_amdgcn_global_load_lds(
            (const __attribute__((address_space(1))) unsigned int*)(src0 + i * 32),
            (__attribute__((address_space(3))) unsigned int*)(d + dst_lane),
            16, 0, 0);
        __builtin_amdgcn_global_load_lds(
            (const __attribute__((address_space(1))) unsigned int*)(src1 + i * 32),
            (__attribute__((address_space(3))) unsigned int*)(d + 1024 + dst_lane),
            16, 0, 0);
    };

    issueA(0);
    issueA(1);
    __syncthreads();   // B + A(0),A(1) all complete (one-time full drain)

    f32x4 acc[4];
#pragma unroll
    for (int nb = 0; nb < 4; ++nb) acc[nb] = (f32x4)0.0f;

    const int ardoff = e0 * 128 + ((g * 32) ^ ((e0 & 3) << 5));   // A frag byte off

    // ---- 8 kk-steps; A tri-buffered, counted vmcnt; B from LDS ----
#pragma unroll
    for (int i = 0; i < 8; ++i) {
        if (i < 6) issueA(i + 2);
        __builtin_amdgcn_sched_barrier(0);
        // outstanding after issue: A(i+1)=2, A(i+2)=2 -> wait leaves 4 in flight
        if (i < 6)       asm volatile("s_waitcnt vmcnt(4)" ::: "memory");
        else if (i == 6) asm volatile("s_waitcnt vmcnt(2)" ::: "memory");
        else             asm volatile("s_waitcnt vmcnt(0)" ::: "memory");
        __builtin_amdgcn_sched_barrier(0);

        const char* ab = Aw + (i % 3) * 2048 + ardoff;
        float4 a0 = *(const float4*)ab;
        float4 a1 = *(const float4*)(ab + 16);
        bf16x8 ah;
        ah[0] = (short)f2bf_hw(a0.x); ah[1] = (short)f2bf_hw(a0.y);
        ah[2] = (short)f2bf_hw(a0.z); ah[3] = (short)f2bf_hw(a0.w);
        ah[4] = (short)f2bf_hw(a1.x); ah[5] = (short)f2bf_hw(a1.y);
        ah[6] = (short)f2bf_hw(a1.z); ah[7] = (short)f2bf_hw(a1.w);

        const unsigned short* bb = &BldsU[i * 2048 + l * 8];
#pragma unroll
        for (int nb = 0; nb < 4; ++nb) {
            bf16x8 bf = *(const bf16x8*)(bb + nb * 512);
            acc[nb] = __builtin_amdgcn_mfma_f32_16x16x32_bf16(ah, bf, acc[nb], 0, 0, 0);
        }
    }

    // ---- store bf16 partials: ushort4 per (token, e0) ----
    ushort4* pp = (ushort4*)part;
#pragma unroll
    for (int r = 0; r < 4; ++r) {
        int t = trow0 + g * 4 + r;               // C/D row = (l>>4)*4 + reg
        ushort4 v;
        v.x = f2bf_rtn(acc[0][r]); v.y = f2bf_rtn(acc[1][r]);
        v.z = f2bf_rtn(acc[2][r]); v.w = f2bf_rtn(acc[3][r]);
        pp[((size_t)kq * N_TOK + t) * 16 + e0] = v;
    }
}

// ---------------------------------------------------------------------------
// Phase 2: reduce 8 bf16 K-partials + gating epilogue.
// Grid 256 x 256 (4 waves). Block: 64 tokens; wave w: 16 tokens.
// Lane (g,e0) handles tokens t = blk*64 + w*16 + g*4 + r, experts nb*16+e0.
// ---------------------------------------------------------------------------
__global__ __launch_bounds__(256, 4)
void gating_epi(const unsigned short* __restrict__ part,
                const float* __restrict__ gates,
                float* __restrict__ out) {
    const int tid = threadIdx.x;
    const int l   = tid & 63;
    const int w   = tid >> 6;
    const int g   = l >> 4;
    const int e0  = l & 15;
    const ushort4* pp = (const ushort4*)part;

    float sig[4];
#pragma unroll
    for (int nb = 0; nb < 4; ++nb)
        sig[nb] = 1.0f / (1.0f + expf(-gates[nb * 16 + e0]));

#pragma unroll
    for (int r = 0; r < 4; ++r) {
        const int t = blockIdx.x * 64 + w * 16 + g * 4 + r;
        float tot[4] = {0.0f, 0.0f, 0.0f, 0.0f};
#pragma unroll
        for (int s = 0; s < 8; ++s) {
            ushort4 v = pp[((size_t)s * N_TOK + t) * 16 + e0];
            tot[0] += bf2f(v.x); tot[1] += bf2f(v.y);
            tot[2] += bf2f(v.z); tot[3] += bf2f(v.w);
        }
        float lg[4] = {tot[0] - sig[0], tot[1] - sig[1],
                       tot[2] - sig[2], tot[3] - sig[3]};
        bool  act[4];
        int   lcnt = 0;
        float lmax = -3.4e38f;
#pragma unroll
        for (int nb = 0; nb < 4; ++nb) {
            act[nb] = lg[nb] > 0.0f;
            if (act[nb]) { lcnt++; lmax = fmaxf(lmax, lg[nb]); }
        }
        int cnt = lcnt;
        float mx = lmax;
#pragma unroll
        for (int m = 1; m < 16; m <<= 1) {
            cnt += __shfl_xor(cnt, m, 16);
            mx   = fmaxf(mx, __shfl_xor(mx, m, 16));
        }

        float p[4], am[4];
        if (cnt > 0) {
            float ex[4], ls = 0.0f;
#pragma unroll
            for (int nb = 0; nb < 4; ++nb) {
                ex[nb] = act[nb] ? expf(lg[nb] - mx) : 0.0f;
                ls += ex[nb];
            }
            float Z = ls;
#pragma unroll
            for (int m = 1; m < 16; m <<= 1) Z += __shfl_xor(Z, m, 16);
            float rz = 1.0f / Z;
#pragma unroll
            for (int nb = 0; nb < 4; ++nb) {
                p[nb]  = ex[nb] * rz;
                am[nb] = act[nb] ? 1.0f : 0.0f;
            }
        } else {
            // fallback: top-32 of 64 logits (ties -> lower expert index);
            // all logits <= 0 here, so probs are uniform 1/32 over the set.
            unsigned selm = 0;
            for (int it = 0; it < 32; ++it) {
                float bv = -3.4e38f;
                int   bi = 127;
#pragma unroll
                for (int nb = 0; nb < 4; ++nb) {
                    if (!((selm >> nb) & 1)) {
                        float v = lg[nb];
                        int   e = nb * 16 + e0;
                        if (v > bv || (v == bv && e < bi)) { bv = v; bi = e; }
                    }
                }
#pragma unroll
                for (int m = 1; m < 16; m <<= 1) {
                    float ov = __shfl_xor(bv, m, 16);
                    int   oi = __shfl_xor(bi, m, 16);
                    if (ov > bv || (ov == bv && oi < bi)) { bv = ov; bi = oi; }
                }
                if ((bi & 15) == e0) selm |= 1u << (bi >> 4);
            }
#pragma unroll
            for (int nb = 0; nb < 4; ++nb) {
                bool s_ = (selm >> nb) & 1;
                p[nb]  = s_ ? (1.0f / 32.0f) : 0.0f;
                am[nb] = s_ ? 1.0f : 0.0f;
            }
            if (e0 == 0) atomicAdd(&out[FB_OFF], 1.0f);
        }

#pragma unroll
        for (int nb = 0; nb < 4; ++nb) {
            int idx = t * 64 + nb * 16 + e0;
            out[idx]          = p[nb];
            out[LG_OFF + idx] = lg[nb];
            out[AM_OFF + idx] = am[nb];
        }
    }
}

// ---------------------------------------------------------------------------
// Fallback mono kernel (R5 structure) if ws_size can't hold the partials.
// ---------------------------------------------------------------------------
__global__ __launch_bounds__(256, 4)
void gating_mono(const float* __restrict__ x,
                 const unsigned short* __restrict__ Bpk,
                 const float* __restrict__ gates,
                 float* __restrict__ out) {
    __shared__ float red[4][16][64];

    const int tid = threadIdx.x;
    const int l   = tid & 63;
    const int w   = tid >> 6;
    const int row0 = blockIdx.x * 16;
    const int g    = l >> 4;
    const int e0   = l & 15;
    const float* xr = x + (size_t)(row0 + e0) * C_DIM + w * 512 + g * 8;
    const unsigned short* bw = Bpk + (size_t)w * 16 * 2048 + l * 8;

    f32x4 acc[4];
#pragma unroll
    for (int nb = 0; nb < 4; ++nb) acc[nb] = (f32x4)0.0f;

    bf16x8 Bf[2][4];
#pragma unroll
    for (int b = 0; b < 2; ++b)
#pragma unroll
        for (int f = 0; f < 4; ++f)
            Bf[b][f] = *(const bf16x8*)(bw + b * 2048 + f * 512);
    float4 Ar[4][2];
#pragma unroll
    for (int it = 0; it < 4; ++it) {
        const float* ap = xr + it * 32;
        Ar[it][0] = *(const float4*)ap;
        Ar[it][1] = *(const float4*)(ap + 4);
    }

#pragma unroll
    for (int it = 0; it < 16; ++it) {
        const int sl = it & 3;
        const int bb = it & 1;
        bf16x8 bnx[4];
        if (it < 14) {
            const unsigned short* bp = bw + (it + 2) * 2048;
#pragma unroll
            for (int f = 0; f < 4; ++f) bnx[f] = *(const bf16x8*)(bp + f * 512);
        }
        float av[8] = {Ar[sl][0].x, Ar[sl][0].y, Ar[sl][0].z, Ar[sl][0].w,
                       Ar[sl][1].x, Ar[sl][1].y, Ar[sl][1].z, Ar[sl][1].w};
        if (it < 12) {
            const float* ap = xr + (it + 4) * 32;
            Ar[sl][0] = *(const float4*)ap;
            Ar[sl][1] = *(const float4*)(ap + 4);
        }
        bf16x8 ah;
#pragma unroll
        for (int i = 0; i < 8; ++i) ah[i] = (short)f2bf_hw(av[i]);
#pragma unroll
        for (int nb = 0; nb < 4; ++nb)
            acc[nb] = __builtin_amdgcn_mfma_f32_16x16x32_bf16(ah, Bf[bb][nb], acc[nb], 0, 0, 0);
        if (it < 14) {
#pragma unroll
            for (int f = 0; f < 4; ++f) Bf[bb][f] = bnx[f];
        }
    }

#pragma unroll
    for (int nb = 0; nb < 4; ++nb)
#pragma unroll
        for (int r = 0; r < 4; ++r)
            red[w][nb * 4 + r][l] = acc[nb][r];
    __syncthreads();

    float tot[4];
#pragma unroll
    for (int nb = 0; nb < 4; ++nb)
        tot[nb] = red[0][nb * 4 + w][l] + red[1][nb * 4 + w][l]
                + red[2][nb * 4 + w][l] + red[3][nb * 4 + w][l];

    float sig[4];
#pragma unroll
    for (int nb = 0; nb < 4; ++nb)
        sig[nb] = 1.0f / (1.0f + expf(-gates[nb * 16 + e0]));

    const int t = row0 + g * 4 + w;
    float lg[4];
    bool  act[4];
    int   lcnt = 0;
    float lmax = -3.4e38f;
#pragma unroll
    for (int nb = 0; nb < 4; ++nb) {
        lg[nb]  = tot[nb] - sig[nb];
        act[nb] = lg[nb] > 0.0f;
        if (act[nb]) { lcnt++; lmax = fmaxf(lmax, lg[nb]); }
    }
    int cnt = lcnt;
    float mx = lmax;
#pragma unroll
    for (int m = 1; m < 16; m <<= 1) {
        cnt += __shfl_xor(cnt, m, 16);
        mx   = fmaxf(mx, __shfl_xor(mx, m, 16));
    }

    float p[4], am[4];
    if (cnt > 0) {
        float ex[4], ls = 0.0f;
#pragma unroll
        for (int nb = 0; nb < 4; ++nb) {
            ex[nb] = act[nb] ? expf(lg[nb] - mx) : 0.0f;
            ls += ex[nb];
        }
        float Z = ls;
#pragma unroll
        for (int m = 1; m < 16; m <<= 1) Z += __shfl_xor(Z, m, 16);
        float rz = 1.0f / Z;
#pragma unroll
        for (int nb = 0; nb < 4; ++nb) {
            p[nb]  = ex[nb] * rz;
            am[nb] = act[nb] ? 1.0f : 0.0f;
        }
    } else {
        unsigned selm = 0;
        for (int it = 0; it < 32; ++it) {
            float bv = -3.4e38f;
            int   bi = 127;
#pragma unroll
            for (int nb = 0; nb < 4; ++nb) {
                if (!((selm >> nb) & 1)) {
                    float v = lg[nb];
                    int   e = nb * 16 + e0;
                    if (v > bv || (v == bv && e < bi)) { bv = v; bi = e; }
                }
            }
#pragma unroll
            for (int m = 1; m < 16; m <<= 1) {
                float ov = __shfl_xor(bv, m, 16);
                int   oi = __shfl_xor(bi, m, 16);
                if (ov > bv || (ov == bv && oi < bi)) { bv = ov; bi = oi; }
            }
            if ((bi & 15) == e0) selm |= 1u << (bi >> 4);
        }
#pragma unroll
        for (int nb = 0; nb < 4; ++nb) {
            bool s_ = (selm >> nb) & 1;
            p[nb]  = s_ ? (1.0f / 32.0f) : 0.0f;
            am[nb] = s_ ? 1.0f : 0.0f;
        }
        if (e0 == 0) atomicAdd(&out[FB_OFF], 1.0f);
    }

#pragma unroll
    for (int nb = 0; nb < 4; ++nb) {
        int idx = t * 64 + nb * 16 + e0;
        out[idx]          = p[nb];
        out[LG_OFF + idx] = lg[nb];
        out[AM_OFF + idx] = am[nb];
    }
}

// ---------------------------------------------------------------------------
extern "C" void kernel_launch(void* const* d_in, const int* in_sizes, int n_in,
                              void* d_out, int out_size, void* d_ws, size_t ws_size,
                              hipStream_t stream) {
    const float* x     = (const float*)d_in[0];   // [4,4096,2048] f32
    const float* sim   = (const float*)d_in[1];   // [2048,64] f32
    const float* gates = (const float*)d_in[2];   // [64] f32
    float* out = (float*)d_out;
    unsigned short* Bpk = (unsigned short*)d_ws;  // 256 KB prepacked B (bf16)

    gating_prepack<<<512, 256, 0, stream>>>(sim, Bpk, out);

    if (ws_size >= BPK_BYTES + PART_BYTES) {
        unsigned short* part = (unsigned short*)((char*)d_ws + BPK_BYTES);
        gating_gemm8<<<1024, 512, 0, stream>>>(x, Bpk, part);
        gating_epi<<<256, 256, 0, stream>>>(part, gates, out);
    } else {
        gating_mono<<<1024, 256, 0, stream>>>(x, Bpk, gates, out);
    }
}

// Round 12
// 38.175 us; speedup vs baseline: 1.1151x; 1.1151x over previous
//
#include <hip/hip_runtime.h>
#include <hip/hip_bf16.h>

// Problem constants (B=4, T=4096, C=2048, E=64)
#define N_TOK   16384
#define C_DIM   2048
#define E_DIM   64
#define P_OFF   (N_TOK * E_DIM)        // 1048576 — end of probs section
#define FB_OFF  P_OFF                  // fallback_count scalar
#define LG_OFF  (P_OFF + 1)            // logits section
#define AM_OFF  (2 * P_OFF + 1)        // activation_mask section

typedef __attribute__((ext_vector_type(8))) short bf16x8;  // 8 bf16 in 4 VGPRs
typedef __attribute__((ext_vector_type(4))) float f32x4;

static __device__ __forceinline__ unsigned short f2bf_rtn(float f) {
    unsigned u = __float_as_uint(f);
    unsigned r = u + 0x7FFFu + ((u >> 16) & 1u);   // round-to-nearest-even
    return (unsigned short)(r >> 16);
}
static __device__ __forceinline__ short f2bf_hw(float f) {
    __hip_bfloat16 h = __float2bfloat16(f);   // HW cvt; pairs fuse to v_cvt_pk_bf16_f32
    return *reinterpret_cast<short*>(&h);
}

// ---------------------------------------------------------------------------
// Kernel 1: prepack sim_matrix [2048,64] f32 -> bf16 (RTN) MFMA fragments.
// kk-step it (32 k): layout [it(64)][nb(4)][lane(64)][i(8)] shorts (256 KB).
// Content: lane l, elem i -> sim[it*32 + (l>>4)*8 + i][nb*16 + (l&15)]
// Also zero-initializes the fallback counter in d_out.
// ---------------------------------------------------------------------------
__global__ void gating_prepack(const float* __restrict__ sim,
                               unsigned short* __restrict__ Bpk,
                               float* __restrict__ out) {
    int tid = blockIdx.x * 256 + threadIdx.x;
    if (tid == 0) out[FB_OFF] = 0.0f;
    if (tid >= C_DIM * E_DIM) return;
    int k = tid >> 6;
    int e = tid & 63;
    float v = sim[tid];                       // sim[k*64 + e]
    int it = k >> 5;                          // kk-step 0..63
    int gr = (k >> 3) & 3;
    int i  = k & 7;
    int lane = gr * 16 + (e & 15);
    int nb   = e >> 4;
    Bpk[it * 2048 + nb * 512 + lane * 8 + i] = f2bf_rtn(v);
}

// ---------------------------------------------------------------------------
// Kernel 2 (R12): max-occupancy mono GEMM + gating epilogue.
//
// 11-round evidence: scheduling never helped (R3/4/6/8/9/11 all neutral);
// only occupancy (R1->R2, 2.2x) and traffic cuts (R4->R5) moved the number.
// Fragment-layout A loads use 100% of each 64B line (4 g-groups cover each
// line), so coalescing was also a non-factor (R5 ~= R10). The kernel is
// memory-queue-bound -> push concurrency to the HW cap: 32 waves/CU.
//
// Grid 1024 x 512 thr (8 waves) = 4 blocks/CU x 8 waves = 2048 thr/CU (max).
// Block = 16 tokens; wave w = K-eighth (256 K = 8 kk-steps), ROLLED loop
// for minimal VGPR (must be <=64 for 32 waves/CU; R3 proved rolled ~44).
// 8-way cross-wave LDS reduction (32 KB; 4 x 32 = 128 <= 160 KB/CU).
// Waves 0-3 run the epilogue for reg r = w; waves 4-7 exit after reduce.
// ---------------------------------------------------------------------------
__global__ __launch_bounds__(512, 8)
void gating_main(const float* __restrict__ x,
                 const unsigned short* __restrict__ Bpk,
                 const float* __restrict__ gates,
                 float* __restrict__ out) {
    __shared__ float red[8][16][64];   // [wave][nb*4+r][lane] = 32 KB

    const int tid = threadIdx.x;
    const int l   = tid & 63;
    const int w   = tid >> 6;          // wave id 0..7 == K-eighth
    const int row0 = blockIdx.x * 16;
    const int g    = l >> 4;           // k-slot group
    const int e0   = l & 15;
    // A: lane's token row, wave's K-eighth; kk-step s reads xr+s*32 (2xfloat4)
    const float* xr = x + (size_t)(row0 + e0) * C_DIM + w * 256 + g * 8;
    // B: kk-step it = w*8+s; per-step stride 2048 shorts; lane frag base
    const unsigned short* bw = Bpk + (size_t)w * 8 * 2048 + l * 8;

    f32x4 acc[4];
#pragma unroll
    for (int nb = 0; nb < 4; ++nb) acc[nb] = (f32x4)0.0f;

    // ---- rolled K loop: 8 kk-steps, minimal registers, TLP hides latency ----
    for (int s = 0; s < 8; ++s) {
        const float* ap = xr + s * 32;
        float4 a0 = *(const float4*)ap;
        float4 a1 = *(const float4*)(ap + 4);
        bf16x8 ah;
        ah[0] = f2bf_hw(a0.x); ah[1] = f2bf_hw(a0.y);
        ah[2] = f2bf_hw(a0.z); ah[3] = f2bf_hw(a0.w);
        ah[4] = f2bf_hw(a1.x); ah[5] = f2bf_hw(a1.y);
        ah[6] = f2bf_hw(a1.z); ah[7] = f2bf_hw(a1.w);

        const unsigned short* bs = bw + s * 2048;
#pragma unroll
        for (int nb = 0; nb < 4; ++nb) {
            bf16x8 bf = *(const bf16x8*)(bs + nb * 512);
            acc[nb] = __builtin_amdgcn_mfma_f32_16x16x32_bf16(ah, bf, acc[nb], 0, 0, 0);
        }
    }

    // ---- cross-wave K reduction via LDS (conflict-free layout) ----
#pragma unroll
    for (int nb = 0; nb < 4; ++nb)
#pragma unroll
        for (int r = 0; r < 4; ++r)
            red[w][nb * 4 + r][l] = acc[nb][r];
    __syncthreads();

    if (w >= 4) return;   // waves 4-7 done (block-uniform per wave)

    float tot[4];
#pragma unroll
    for (int nb = 0; nb < 4; ++nb) {
        float t0 = 0.0f;
#pragma unroll
        for (int s = 0; s < 8; ++s) t0 += red[s][nb * 4 + w][l];
        tot[nb] = t0;
    }

    // ---- epilogue: wave w (0..3) handles tokens t = row0 + g*4 + w ----
    float sig[4];
#pragma unroll
    for (int nb = 0; nb < 4; ++nb)
        sig[nb] = 1.0f / (1.0f + expf(-gates[nb * 16 + e0]));

    const int t = row0 + g * 4 + w;
    float lg[4];
    bool  act[4];
    int   lcnt = 0;
    float lmax = -3.4e38f;
#pragma unroll
    for (int nb = 0; nb < 4; ++nb) {
        lg[nb]  = tot[nb] - sig[nb];
        act[nb] = lg[nb] > 0.0f;
        if (act[nb]) { lcnt++; lmax = fmaxf(lmax, lg[nb]); }
    }
    int cnt = lcnt;
    float mx = lmax;
#pragma unroll
    for (int m = 1; m < 16; m <<= 1) {
        cnt += __shfl_xor(cnt, m, 16);
        mx   = fmaxf(mx, __shfl_xor(mx, m, 16));
    }

    float p[4], am[4];
    if (cnt > 0) {
        float ex[4], ls = 0.0f;
#pragma unroll
        for (int nb = 0; nb < 4; ++nb) {
            ex[nb] = act[nb] ? expf(lg[nb] - mx) : 0.0f;
            ls += ex[nb];
        }
        float Z = ls;
#pragma unroll
        for (int m = 1; m < 16; m <<= 1) Z += __shfl_xor(Z, m, 16);
        float rz = 1.0f / Z;
#pragma unroll
        for (int nb = 0; nb < 4; ++nb) {
            p[nb]  = ex[nb] * rz;
            am[nb] = act[nb] ? 1.0f : 0.0f;
        }
    } else {
        // fallback: top-32 of the 64 logits (ties -> lower expert index).
        // All logits <= 0 here, so probs are uniform 1/32 over the set.
        unsigned selm = 0;
        for (int it = 0; it < 32; ++it) {
            float bv = -3.4e38f;
            int   bi = 127;
#pragma unroll
            for (int nb = 0; nb < 4; ++nb) {
                if (!((selm >> nb) & 1)) {
                    float v = lg[nb];
                    int   e = nb * 16 + e0;
                    if (v > bv || (v == bv && e < bi)) { bv = v; bi = e; }
                }
            }
#pragma unroll
            for (int m = 1; m < 16; m <<= 1) {
                float ov = __shfl_xor(bv, m, 16);
                int   oi = __shfl_xor(bi, m, 16);
                if (ov > bv || (ov == bv && oi < bi)) { bv = ov; bi = oi; }
            }
            if ((bi & 15) == e0) selm |= 1u << (bi >> 4);
        }
#pragma unroll
        for (int nb = 0; nb < 4; ++nb) {
            bool s_ = (selm >> nb) & 1;
            p[nb]  = s_ ? (1.0f / 32.0f) : 0.0f;
            am[nb] = s_ ? 1.0f : 0.0f;
        }
        if (e0 == 0) atomicAdd(&out[FB_OFF], 1.0f);
    }

#pragma unroll
    for (int nb = 0; nb < 4; ++nb) {
        int idx = t * 64 + nb * 16 + e0;
        out[idx]          = p[nb];
        out[LG_OFF + idx] = lg[nb];
        out[AM_OFF + idx] = am[nb];
    }
}

// ---------------------------------------------------------------------------
extern "C" void kernel_launch(void* const* d_in, const int* in_sizes, int n_in,
                              void* d_out, int out_size, void* d_ws, size_t ws_size,
                              hipStream_t stream) {
    const float* x     = (const float*)d_in[0];   // [4,4096,2048] f32
    const float* sim   = (const float*)d_in[1];   // [2048,64] f32
    const float* gates = (const float*)d_in[2];   // [64] f32
    float* out = (float*)d_out;
    unsigned short* Bpk = (unsigned short*)d_ws;  // 256 KB prepacked B (bf16)

    gating_prepack<<<512, 256, 0, stream>>>(sim, Bpk, out);
    gating_main<<<1024, 512, 0, stream>>>(x, Bpk, gates, out);
}